// Round 5
// baseline (339.726 us; speedup 1.0000x reference)
//
#include <hip/hip_runtime.h>

// Trilinear forward-splat, two-phase (scatter->ws tiles, then gather).
// Reference semantics (exact):
//   locs = max(grid + flow, 0)
//   delta = locs - floor(locs)           (from UNclamped floor)
//   base  = min((int)floor(locs), dim-1)
//   corner per axis = min(base + {0,1}, dim-1)   (collapsed corners add twice)
//
// Phase 1: block owns 8x8x64 chunk, scatters into LDS tile (12x12x68, halo 2)
//          via ds_add_f32; writes the WHOLE tile to ws with float4 stores
//          (no global atomics). Rare out-of-tile corners -> global atomic on out.
// Phase 2: gather: out[c] = out[c](outliers) + sum over <=8 covering tiles.
// Host falls back to single-kernel atomic flush if ws is too small.

constexpr int H = 192, W = 192, Dd = 192;
constexpr int N = H * W * Dd;
constexpr int WD = W * Dd;

constexpr int BI = 8, BJ = 8, BK = 64;       // source chunk per block
constexpr int NBI = H / BI, NBJ = W / BJ, NBK = Dd / BK;  // 24,24,3
constexpr int HL = 2;                        // halo radius
constexpr int TI = BI + 2 * HL;              // 12
constexpr int TJ = BJ + 2 * HL;              // 12
constexpr int TK = BK + 2 * HL;              // 68
constexpr int TCELLS = TI * TJ * TK;         // 9792 floats = 38.25 KB
constexpr int NBLOCKS = NBI * NBJ * NBK;     // 1728
constexpr size_t WS_NEEDED = (size_t)NBLOCKS * TCELLS * sizeof(float);  // 67.7 MB

// ---- shared scatter body: fills LDS tile, deposits outliers to out ----
__device__ __forceinline__ void scatter_to_tile(float* tile,
                                                const float* __restrict__ src,
                                                const float* __restrict__ flow,
                                                float* __restrict__ out,
                                                int t, int i0, int j0, int k0,
                                                int xg0, int yg0, int zg0) {
#pragma unroll
    for (int p = 0; p < 2; ++p) {
        const int g  = p * 512 + t;            // float4-group index, 0..1023
        const int kg = (g & 15) * 4;           // 0..60
        const int cj = (g >> 4) & 7;
        const int ci = g >> 7;                 // 0..7
        const int i = i0 + ci, j = j0 + cj, k = k0 + kg;
        const int off = i * WD + j * Dd + k;

        const float4 s4  = *reinterpret_cast<const float4*>(src + off);
        const float4 fx4 = *reinterpret_cast<const float4*>(flow + off);
        const float4 fy4 = *reinterpret_cast<const float4*>(flow + N + off);
        const float4 fz4 = *reinterpret_cast<const float4*>(flow + 2 * N + off);

        const float sa[4]  = {s4.x, s4.y, s4.z, s4.w};
        const float fxa[4] = {fx4.x, fx4.y, fx4.z, fx4.w};
        const float fya[4] = {fy4.x, fy4.y, fy4.z, fy4.w};
        const float fza[4] = {fz4.x, fz4.y, fz4.z, fz4.w};

#pragma unroll
        for (int q = 0; q < 4; ++q) {
            const float lx = fmaxf((float)i       + fxa[q], 0.0f);
            const float ly = fmaxf((float)j       + fya[q], 0.0f);
            const float lz = fmaxf((float)(k + q) + fza[q], 0.0f);

            const float bx = floorf(lx), by = floorf(ly), bz = floorf(lz);
            const float dx = lx - bx,    dy = ly - by,    dz = lz - bz;

            const int x0 = min((int)bx, H - 1);
            const int y0 = min((int)by, W - 1);
            const int z0 = min((int)bz, Dd - 1);
            const int x1 = min(x0 + 1, H - 1);
            const int y1 = min(y0 + 1, W - 1);
            const int z1 = min(z0 + 1, Dd - 1);

            const float s = sa[q];
            const float wx0 = 1.0f - dx, wy0 = 1.0f - dy, wz0 = 1.0f - dz;
            const float a00 = s * wx0 * wy0;
            const float a01 = s * wx0 * dy;
            const float a10 = s * dx * wy0;
            const float a11 = s * dx * dy;

            const float v000 = a00 * wz0, v001 = a00 * dz;
            const float v010 = a01 * wz0, v011 = a01 * dz;
            const float v100 = a10 * wz0, v101 = a10 * dz;
            const float v110 = a11 * wz0, v111 = a11 * dz;

            const int a0 = x0 - xg0, a1 = x1 - xg0;
            const int b0 = y0 - yg0, b1 = y1 - yg0;
            const int c0 = z0 - zg0, c1 = z1 - zg0;

            const bool fast = ((unsigned)a0 < (unsigned)TI) & ((unsigned)a1 < (unsigned)TI) &
                              ((unsigned)b0 < (unsigned)TJ) & ((unsigned)b1 < (unsigned)TJ) &
                              ((unsigned)c0 < (unsigned)TK) & ((unsigned)c1 < (unsigned)TK);

            if (__builtin_expect(fast, 1)) {
                const int r00 = (a0 * TJ + b0) * TK;
                const int r01 = (a0 * TJ + b1) * TK;
                const int r10 = (a1 * TJ + b0) * TK;
                const int r11 = (a1 * TJ + b1) * TK;
                atomicAdd(&tile[r00 + c0], v000);
                atomicAdd(&tile[r00 + c1], v001);
                atomicAdd(&tile[r01 + c0], v010);
                atomicAdd(&tile[r01 + c1], v011);
                atomicAdd(&tile[r10 + c0], v100);
                atomicAdd(&tile[r10 + c1], v101);
                atomicAdd(&tile[r11 + c0], v110);
                atomicAdd(&tile[r11 + c1], v111);
            } else {
                const int   xs[2] = {x0, x1}, ys[2] = {y0, y1}, zs[2] = {z0, z1};
                const float vs[8] = {v000, v001, v010, v011, v100, v101, v110, v111};
#pragma unroll
                for (int c = 0; c < 8; ++c) {
                    const int xx = xs[(c >> 2) & 1], yy = ys[(c >> 1) & 1], zz = zs[c & 1];
                    const int ta = xx - xg0, tb = yy - yg0, tc = zz - zg0;
                    if (((unsigned)ta < (unsigned)TI) & ((unsigned)tb < (unsigned)TJ) &
                        ((unsigned)tc < (unsigned)TK)) {
                        atomicAdd(&tile[(ta * TJ + tb) * TK + tc], vs[c]);
                    } else {
                        unsafeAtomicAdd(out + xx * WD + yy * Dd + zz, vs[c]);
                    }
                }
            }
        }
    }
}

// ---- Phase 1: scatter, flush whole tile to ws (no atomics) ----
__global__ __launch_bounds__(512, 8) void splat_ws_kernel(const float* __restrict__ src,
                                                          const float* __restrict__ flow,
                                                          float* __restrict__ out,
                                                          float* __restrict__ ws) {
    __shared__ __align__(16) float tile[TCELLS];
    const int t  = threadIdx.x;
    const int bk = blockIdx.x, bj = blockIdx.y, bi = blockIdx.z;
    const int i0 = bi * BI, j0 = bj * BJ, k0 = bk * BK;
    const int xg0 = i0 - HL, yg0 = j0 - HL, zg0 = k0 - HL;

    {
        const float4 z4 = make_float4(0.f, 0.f, 0.f, 0.f);
        float4* t4 = reinterpret_cast<float4*>(tile);
        for (int c = t; c < TCELLS / 4; c += 512) t4[c] = z4;
    }
    __syncthreads();

    scatter_to_tile(tile, src, flow, out, t, i0, j0, k0, xg0, yg0, zg0);
    __syncthreads();

    const int lb = (bi * NBJ + bj) * NBK + bk;
    float4* wt = reinterpret_cast<float4*>(ws + (size_t)lb * TCELLS);
    const float4* t4 = reinterpret_cast<const float4*>(tile);
    for (int c = t; c < TCELLS / 4; c += 512) wt[c] = t4[c];
}

// ---- Phase 2: gather tiles -> out (adds onto outlier deposits) ----
__global__ __launch_bounds__(256) void gather_kernel(const float* __restrict__ ws,
                                                     float* __restrict__ out) {
    const int tid = blockIdx.x * 256 + threadIdx.x;
    const int n0 = tid * 4;
    if (n0 >= N) return;
    const int i   = n0 / WD;
    const int rem = n0 - i * WD;
    const int j   = rem / Dd;
    const int z0  = rem - j * Dd;   // multiple of 4

    const float4 o4 = *reinterpret_cast<const float4*>(out + n0);
    float acc[4] = {o4.x, o4.y, o4.z, o4.w};

    const int biA = (i + 2) >> 3;
    const int bjA = (j + 2) >> 3;

#pragma unroll
    for (int dbi = 0; dbi < 2; ++dbi) {
        const int bi = biA - dbi;
        if ((unsigned)bi >= (unsigned)NBI) continue;
        const int a = i - (bi * BI - HL);
        if ((unsigned)a >= (unsigned)TI) continue;
#pragma unroll
        for (int dbj = 0; dbj < 2; ++dbj) {
            const int bj = bjA - dbj;
            if ((unsigned)bj >= (unsigned)NBJ) continue;
            const int b = j - (bj * BJ - HL);
            if ((unsigned)b >= (unsigned)TJ) continue;

            const float* tbase = ws + (size_t)(bi * NBJ + bj) * NBK * TCELLS
                               + (a * TJ + b) * TK;
#pragma unroll
            for (int q = 0; q < 4; ++q) {
                const int z = z0 + q;
                const int bkA = (z + 2) >> 6;
#pragma unroll
                for (int dbk = 0; dbk < 2; ++dbk) {
                    const int bk = bkA - dbk;
                    if ((unsigned)bk >= (unsigned)NBK) continue;
                    const int c = z - (bk * BK - HL);
                    if ((unsigned)c >= (unsigned)TK) continue;
                    acc[q] += tbase[(size_t)bk * TCELLS + c];
                }
            }
        }
    }
    *reinterpret_cast<float4*>(out + n0) = make_float4(acc[0], acc[1], acc[2], acc[3]);
}

// ---- fallback (R4): atomic flush straight to out ----
__global__ __launch_bounds__(512, 8) void splat_atomic_kernel(const float* __restrict__ src,
                                                              const float* __restrict__ flow,
                                                              float* __restrict__ out) {
    __shared__ __align__(16) float tile[TCELLS];
    const int t  = threadIdx.x;
    const int bk = blockIdx.x, bj = blockIdx.y, bi = blockIdx.z;
    const int i0 = bi * BI, j0 = bj * BJ, k0 = bk * BK;
    const int xg0 = i0 - HL, yg0 = j0 - HL, zg0 = k0 - HL;

    {
        const float4 z4 = make_float4(0.f, 0.f, 0.f, 0.f);
        float4* t4 = reinterpret_cast<float4*>(tile);
        for (int c = t; c < TCELLS / 4; c += 512) t4[c] = z4;
    }
    __syncthreads();

    scatter_to_tile(tile, src, flow, out, t, i0, j0, k0, xg0, yg0, zg0);
    __syncthreads();

    for (int c = t; c < TCELLS; c += 512) {
        const float v = tile[c];
        if (v != 0.0f) {
            const int tk = c % TK;
            const int rest = c / TK;
            const int tj = rest % TJ;
            const int ti = rest / TJ;
            const int x = xg0 + ti, y = yg0 + tj, z = zg0 + tk;
            if (((unsigned)x < (unsigned)H) & ((unsigned)y < (unsigned)W) &
                ((unsigned)z < (unsigned)Dd)) {
                unsafeAtomicAdd(out + x * WD + y * Dd + z, v);
            }
        }
    }
}

extern "C" void kernel_launch(void* const* d_in, const int* in_sizes, int n_in,
                              void* d_out, int out_size, void* d_ws, size_t ws_size,
                              hipStream_t stream) {
    const float* src  = (const float*)d_in[0];
    const float* flow = (const float*)d_in[1];
    float* out = (float*)d_out;

    // out must start zeroed every call (outlier atomics land on it; harness
    // doesn't re-poison between replays).
    hipMemsetAsync(out, 0, (size_t)N * sizeof(float), stream);

    const dim3 block(512);
    const dim3 grid(NBK, NBJ, NBI);  // (3, 24, 24) = 1728 blocks

    if (ws_size >= WS_NEEDED) {
        float* ws = (float*)d_ws;
        splat_ws_kernel<<<grid, block, 0, stream>>>(src, flow, out, ws);
        const int gthreads = N / 4;
        gather_kernel<<<(gthreads + 255) / 256, 256, 0, stream>>>(ws, out);
    } else {
        splat_atomic_kernel<<<grid, block, 0, stream>>>(src, flow, out);
    }
}